// Round 18
// baseline (66.338 us; speedup 1.0000x reference)
//
#include <hip/hip_runtime.h>
#include <math.h>

#define LL 768
#define CT 64
#define KD 192
#define OC 1024
#define TS 16
#define NST 48           // 768/16 tiles per dim
#define PCH 68           // partial line: 64 ch + z at [64]

typedef float vf4 __attribute__((ext_vector_type(4)));   // native vector for nt builtins

// 16-lane-group sum via DPP: quad_perm(xor1), quad_perm(xor2), row_ror:4,
// row_ror:8 — pure VALU. On-device verified (R6/R9).
__device__ __forceinline__ float sum16(float x) {
    x += __int_as_float(__builtin_amdgcn_update_dpp(0, __float_as_int(x), 0xB1, 0xF, 0xF, true));
    x += __int_as_float(__builtin_amdgcn_update_dpp(0, __float_as_int(x), 0x4E, 0xF, 0xF, true));
    x += __int_as_float(__builtin_amdgcn_update_dpp(0, __float_as_int(x), 0x124, 0xF, 0xF, true));
    x += __int_as_float(__builtin_amdgcn_update_dpp(0, __float_as_int(x), 0x128, 0xF, 0xF, true));
    return x;
}

__device__ __forceinline__ vf4 ntload4(const float* p) {
    return __builtin_nontemporal_load(reinterpret_cast<const vf4*>(p));
}

// ---------------- K1: fused pass (R15 structure) + NONTEMPORAL feat loads ------
// Single delta vs R15: feat loads set the nt bit -> bypass L2/L3 line
// allocation. feat is read exactly once per replay (harness reset-fills evict
// it between replays), so nt is semantically ideal; this isolates whether the
// ~3.1 TB/s read plateau is the cache-fill path or DRAM itself.
__global__ __launch_bounds__(256) void k_fused(const float* __restrict__ feat,
                                               const float* __restrict__ Wq,
                                               const float* __restrict__ bq,
                                               float* __restrict__ rp,
                                               float* __restrict__ cp) {
    __shared__ float cpart[4][16][68];   // [wave][j-in-tile][64ch + z]

    int t = threadIdx.x;
    int w = t >> 6, ln = t & 63;
    int g = ln >> 4, q = ln & 15;
    int bj = blockIdx.x, bi = blockIdx.y;   // bj fast (R12 mapping)
    int i0 = bi * TS, j0 = bj * TS;

    const float4 wq = *reinterpret_cast<const float4*>(Wq + q * 4);
    const float bqv = bq[0];

    float4 c0 = make_float4(0,0,0,0), c1 = make_float4(0,0,0,0);
    float4 c2 = make_float4(0,0,0,0), c3 = make_float4(0,0,0,0);
    float zc0 = 0.f, zc1 = 0.f, zc2 = 0.f, zc3 = 0.f;

    #define STEP(F, CR, ZC)                                              \
        {                                                                \
            float s = F.x * wq.x + F.y * wq.y + F.z * wq.z + F.w * wq.w; \
            s = sum16(s);                                                \
            float e = __expf(s + bqv);                                   \
            racc.x = fmaf(e, F.x, racc.x);                               \
            racc.y = fmaf(e, F.y, racc.y);                               \
            racc.z = fmaf(e, F.z, racc.z);                               \
            racc.w = fmaf(e, F.w, racc.w);                               \
            zr += e;                                                     \
            CR.x = fmaf(e, F.x, CR.x);                                   \
            CR.y = fmaf(e, F.y, CR.y);                                   \
            CR.z = fmaf(e, F.z, CR.z);                                   \
            CR.w = fmaf(e, F.w, CR.w);                                   \
            ZC += e;                                                     \
        }

    #pragma unroll
    for (int r = 0; r < 4; ++r) {
        const int row = i0 + w * 4 + r;
        const float* fb = feat + ((size_t)row * LL + j0 + g) * CT + q * 4;

        const vf4 f0 = ntload4(fb + 0 * 4 * CT);
        const vf4 f1 = ntload4(fb + 1 * 4 * CT);
        const vf4 f2 = ntload4(fb + 2 * 4 * CT);
        const vf4 f3 = ntload4(fb + 3 * 4 * CT);

        float4 racc = make_float4(0,0,0,0);
        float zr = 0.f;
        STEP(f0, c0, zc0)
        STEP(f1, c1, zc1)
        STEP(f2, c2, zc2)
        STEP(f3, c3, zc3)

        // row fold over the 4 j-groups (wave-local, register-only chain)
        racc.x += __shfl_xor(racc.x, 16); racc.x += __shfl_xor(racc.x, 32);
        racc.y += __shfl_xor(racc.y, 16); racc.y += __shfl_xor(racc.y, 32);
        racc.z += __shfl_xor(racc.z, 16); racc.z += __shfl_xor(racc.z, 32);
        racc.w += __shfl_xor(racc.w, 16); racc.w += __shfl_xor(racc.w, 32);
        zr     += __shfl_xor(zr, 16);     zr     += __shfl_xor(zr, 32);

        if (g == 0) {
            size_t ro = ((size_t)row * NST + bj) * PCH;
            *reinterpret_cast<float4*>(rp + ro + q * 4) = racc;
            if (q == 0) rp[ro + 64] = zr;
        }
    }
    #undef STEP

    // col partials -> LDS (one write per jb), single barrier, cross-wave fold
    *reinterpret_cast<float4*>(&cpart[w][0 * 4 + g][q * 4]) = c0;
    *reinterpret_cast<float4*>(&cpart[w][1 * 4 + g][q * 4]) = c1;
    *reinterpret_cast<float4*>(&cpart[w][2 * 4 + g][q * 4]) = c2;
    *reinterpret_cast<float4*>(&cpart[w][3 * 4 + g][q * 4]) = c3;
    if (q == 0) {
        cpart[w][0 * 4 + g][64] = zc0;
        cpart[w][1 * 4 + g][64] = zc1;
        cpart[w][2 * 4 + g][64] = zc2;
        cpart[w][3 * 4 + g][64] = zc3;
    }
    __syncthreads();

    {
        int jj = t >> 4, c4 = t & 15;
        const float4 a0 = *reinterpret_cast<const float4*>(&cpart[0][jj][c4 * 4]);
        const float4 a1 = *reinterpret_cast<const float4*>(&cpart[1][jj][c4 * 4]);
        const float4 a2 = *reinterpret_cast<const float4*>(&cpart[2][jj][c4 * 4]);
        const float4 a3 = *reinterpret_cast<const float4*>(&cpart[3][jj][c4 * 4]);
        float4 a;
        a.x = (a0.x + a1.x) + (a2.x + a3.x);
        a.y = (a0.y + a1.y) + (a2.y + a3.y);
        a.z = (a0.z + a1.z) + (a2.z + a3.z);
        a.w = (a0.w + a1.w) + (a2.w + a3.w);
        size_t co = ((size_t)(j0 + jj) * NST + bi) * PCH;
        *reinterpret_cast<float4*>(cp + co + c4 * 4) = a;
        if (c4 == 0)
            cp[co + 64] = cpart[0][jj][64] + cpart[1][jj][64]
                        + cpart[2][jj][64] + cpart[3][jj][64];
    }
}

// ---------------- K2: fold 48 strip-partials (line-major), /z -> rcfeat -------
__global__ __launch_bounds__(256) void k_combine(const float* __restrict__ rp,
                                                 const float* __restrict__ cp,
                                                 float* __restrict__ rcfeat) {
    int t = threadIdx.x;
    int r = t >> 4, q = t & 15;
    int L = blockIdx.x * 16 + r;
    int side = blockIdx.y;
    const float* base = (side ? cp : rp) + (size_t)L * NST * PCH;

    float4 acc = make_float4(0.f, 0.f, 0.f, 0.f);
    float z = 0.f;
    #pragma unroll 4
    for (int s = 0; s < NST; ++s) {
        const float4 v = *reinterpret_cast<const float4*>(base + s * PCH + q * 4);
        acc.x += v.x; acc.y += v.y; acc.z += v.z; acc.w += v.w;
        z += base[s * PCH + 64];
    }
    float inv = 1.0f / z;
    acc.x *= inv; acc.y *= inv; acc.z *= inv; acc.w *= inv;
    *reinterpret_cast<float4*>(rcfeat + (size_t)side * LL * CT
                               + (size_t)L * CT + q * 4) = acc;
}

// ---------------- K3: diag gather + LN + (x @ W + b) [*sigma] ----------------
__global__ __launch_bounds__(256) void k_final(const float* __restrict__ feat,
                                               const float* __restrict__ rcfeat,
                                               const float* __restrict__ ln_g,
                                               const float* __restrict__ ln_b,
                                               const float* __restrict__ WU,
                                               const float* __restrict__ bU,
                                               const float* __restrict__ WV,
                                               const float* __restrict__ bV,
                                               const float* __restrict__ sigma,
                                               float* __restrict__ out) {
    __shared__ float xbuf[8][KD];
    int t = threadIdx.x;
    int wid = t >> 6, l = t & 63;
    int r0 = blockIdx.x * 8;
    int right = blockIdx.y;
    const float* rfeat = rcfeat;
    const float* cfeat = rcfeat + LL * CT;

    for (int r = wid; r < 8; r += 4) {
        int i = r0 + r;
        float d  = feat[((size_t)i * LL + i) * CT + l];
        float rv = rfeat[(size_t)i * CT + l];
        float cv = cfeat[(size_t)i * CT + l];
        float sum = d + rv + cv;
        #pragma unroll
        for (int o = 32; o; o >>= 1) sum += __shfl_xor(sum, o);
        float mu = sum * (1.0f / 192.0f);
        float d0 = d - mu, d1 = rv - mu, d2 = cv - mu;
        float sq = d0 * d0 + d1 * d1 + d2 * d2;
        #pragma unroll
        for (int o = 32; o; o >>= 1) sq += __shfl_xor(sq, o);
        float rstd = rsqrtf(sq * (1.0f / 192.0f) + 1e-5f);
        float h0 = d0 * rstd, h1 = d1 * rstd, h2 = d2 * rstd;
        float a1 = right ? h2 : h1;
        float a2 = right ? h1 : h2;
        xbuf[r][l]       = h0 * ln_g[l]       + ln_b[l];
        xbuf[r][64 + l]  = a1 * ln_g[64 + l]  + ln_b[64 + l];
        xbuf[r][128 + l] = a2 * ln_g[128 + l] + ln_b[128 + l];
    }
    __syncthreads();

    const float* W    = right ? WV : WU;
    const float* bias = right ? bV : bU;
    int o = blockIdx.z * 512 + t * 2;       // 2 columns per thread
    float2 acc[8];
    #pragma unroll
    for (int r = 0; r < 8; ++r) acc[r] = make_float2(0.f, 0.f);

    for (int k = 0; k < KD; k += 4) {
        float4 xr[8];
        #pragma unroll
        for (int r = 0; r < 8; ++r)
            xr[r] = *reinterpret_cast<const float4*>(&xbuf[r][k]);
        #pragma unroll
        for (int kk = 0; kk < 4; ++kk) {
            const float2 wv = *reinterpret_cast<const float2*>(W + (size_t)(k + kk) * OC + o);
            #pragma unroll
            for (int r = 0; r < 8; ++r) {
                float xv = (&xr[r].x)[kk];
                acc[r].x = fmaf(xv, wv.x, acc[r].x);
                acc[r].y = fmaf(xv, wv.y, acc[r].y);
            }
        }
    }

    const float2 bb = *reinterpret_cast<const float2*>(bias + o);
    float sg = right ? 1.0f : sigma[o >> 7];
    float* obase = out + (right ? (size_t)LL * OC : 0);
    #pragma unroll
    for (int r = 0; r < 8; ++r) {
        float2 v;
        v.x = (acc[r].x + bb.x) * sg;
        v.y = (acc[r].y + bb.y) * sg;
        *reinterpret_cast<float2*>(obase + (size_t)(r0 + r) * OC + o) = v;
    }
}

extern "C" void kernel_launch(void* const* d_in, const int* in_sizes, int n_in,
                              void* d_out, int out_size, void* d_ws, size_t ws_size,
                              hipStream_t stream) {
    const float* feat  = (const float*)d_in[0];
    const float* Wq    = (const float*)d_in[1];
    const float* bq    = (const float*)d_in[2];
    const float* ln_g  = (const float*)d_in[3];
    const float* ln_b  = (const float*)d_in[4];
    const float* WU    = (const float*)d_in[5];
    const float* bU    = (const float*)d_in[6];
    const float* WV    = (const float*)d_in[7];
    const float* bV    = (const float*)d_in[8];
    const float* sigma = (const float*)d_in[9];
    float* out = (float*)d_out;

    float* ws     = (float*)d_ws;
    float* rp     = ws;                                  // LL*NST*PCH
    float* cp     = rp + (size_t)LL * NST * PCH;         // LL*NST*PCH
    float* rcfeat = cp + (size_t)LL * NST * PCH;         // 2*LL*CT

    hipLaunchKernelGGL(k_fused, dim3(NST, NST), dim3(256), 0, stream,
                       feat, Wq, bq, rp, cp);
    hipLaunchKernelGGL(k_combine, dim3(LL / 16, 2), dim3(256), 0, stream,
                       rp, cp, rcfeat);
    hipLaunchKernelGGL(k_final, dim3(LL / 8, 2, 2), dim3(256), 0, stream,
                       feat, rcfeat, ln_g, ln_b, WU, bU, WV, bV, sigma, out);
}

// Round 19
// 61.314 us; speedup vs baseline: 1.0819x; 1.0819x over previous
//
#include <hip/hip_runtime.h>
#include <math.h>

#define LL 768
#define CT 64
#define KD 192
#define OC 1024
#define TS 16
#define NST 48           // 768/16 tiles per dim
#define PCH 68           // partial line: 64 ch + z at [64]

// 16-lane-group sum via DPP: quad_perm(xor1), quad_perm(xor2), row_ror:4,
// row_ror:8 — pure VALU. On-device verified (R6/R9).
__device__ __forceinline__ float sum16(float x) {
    x += __int_as_float(__builtin_amdgcn_update_dpp(0, __float_as_int(x), 0xB1, 0xF, 0xF, true));
    x += __int_as_float(__builtin_amdgcn_update_dpp(0, __float_as_int(x), 0x4E, 0xF, 0xF, true));
    x += __int_as_float(__builtin_amdgcn_update_dpp(0, __float_as_int(x), 0x124, 0xF, 0xF, true));
    x += __int_as_float(__builtin_amdgcn_update_dpp(0, __float_as_int(x), 0x128, 0xF, 0xF, true));
    return x;
}

// ---------------- K1: fused pass, wave-owned rows, ONE barrier per tile --------
// Best measured config (R15, 61.3us): cached loads (nt was -5us, R18), 16x16
// tile, wave w owns rows i0+4w..4w+3, single end-of-tile barrier, line-major
// partials. k_fused runs at ~92% of the ~3.3 TB/s chip read ceiling
// (m13 copy = 3.15 TB/s reads — same wall).
__global__ __launch_bounds__(256) void k_fused(const float* __restrict__ feat,
                                               const float* __restrict__ Wq,
                                               const float* __restrict__ bq,
                                               float* __restrict__ rp,
                                               float* __restrict__ cp) {
    __shared__ float cpart[4][16][68];   // [wave][j-in-tile][64ch + z]

    int t = threadIdx.x;
    int w = t >> 6, ln = t & 63;
    int g = ln >> 4, q = ln & 15;
    int bj = blockIdx.x, bi = blockIdx.y;   // bj fast (R12 mapping)
    int i0 = bi * TS, j0 = bj * TS;

    const float4 wq = *reinterpret_cast<const float4*>(Wq + q * 4);
    const float bqv = bq[0];

    float4 c0 = make_float4(0,0,0,0), c1 = make_float4(0,0,0,0);
    float4 c2 = make_float4(0,0,0,0), c3 = make_float4(0,0,0,0);
    float zc0 = 0.f, zc1 = 0.f, zc2 = 0.f, zc3 = 0.f;

    #define STEP(F, CR, ZC)                                              \
        {                                                                \
            float s = F.x * wq.x + F.y * wq.y + F.z * wq.z + F.w * wq.w; \
            s = sum16(s);                                                \
            float e = __expf(s + bqv);                                   \
            racc.x = fmaf(e, F.x, racc.x);                               \
            racc.y = fmaf(e, F.y, racc.y);                               \
            racc.z = fmaf(e, F.z, racc.z);                               \
            racc.w = fmaf(e, F.w, racc.w);                               \
            zr += e;                                                     \
            CR.x = fmaf(e, F.x, CR.x);                                   \
            CR.y = fmaf(e, F.y, CR.y);                                   \
            CR.z = fmaf(e, F.z, CR.z);                                   \
            CR.w = fmaf(e, F.w, CR.w);                                   \
            ZC += e;                                                     \
        }

    #pragma unroll
    for (int r = 0; r < 4; ++r) {
        const int row = i0 + w * 4 + r;
        const float* fb = feat + ((size_t)row * LL + j0 + g) * CT + q * 4;

        const float4 f0 = *reinterpret_cast<const float4*>(fb + 0 * 4 * CT);
        const float4 f1 = *reinterpret_cast<const float4*>(fb + 1 * 4 * CT);
        const float4 f2 = *reinterpret_cast<const float4*>(fb + 2 * 4 * CT);
        const float4 f3 = *reinterpret_cast<const float4*>(fb + 3 * 4 * CT);

        float4 racc = make_float4(0,0,0,0);
        float zr = 0.f;
        STEP(f0, c0, zc0)
        STEP(f1, c1, zc1)
        STEP(f2, c2, zc2)
        STEP(f3, c3, zc3)

        // row fold over the 4 j-groups (wave-local, register-only chain)
        racc.x += __shfl_xor(racc.x, 16); racc.x += __shfl_xor(racc.x, 32);
        racc.y += __shfl_xor(racc.y, 16); racc.y += __shfl_xor(racc.y, 32);
        racc.z += __shfl_xor(racc.z, 16); racc.z += __shfl_xor(racc.z, 32);
        racc.w += __shfl_xor(racc.w, 16); racc.w += __shfl_xor(racc.w, 32);
        zr     += __shfl_xor(zr, 16);     zr     += __shfl_xor(zr, 32);

        if (g == 0) {
            size_t ro = ((size_t)row * NST + bj) * PCH;
            *reinterpret_cast<float4*>(rp + ro + q * 4) = racc;
            if (q == 0) rp[ro + 64] = zr;
        }
    }
    #undef STEP

    // col partials -> LDS (one write per jb), single barrier, cross-wave fold
    *reinterpret_cast<float4*>(&cpart[w][0 * 4 + g][q * 4]) = c0;
    *reinterpret_cast<float4*>(&cpart[w][1 * 4 + g][q * 4]) = c1;
    *reinterpret_cast<float4*>(&cpart[w][2 * 4 + g][q * 4]) = c2;
    *reinterpret_cast<float4*>(&cpart[w][3 * 4 + g][q * 4]) = c3;
    if (q == 0) {
        cpart[w][0 * 4 + g][64] = zc0;
        cpart[w][1 * 4 + g][64] = zc1;
        cpart[w][2 * 4 + g][64] = zc2;
        cpart[w][3 * 4 + g][64] = zc3;
    }
    __syncthreads();

    {
        int jj = t >> 4, c4 = t & 15;
        const float4 a0 = *reinterpret_cast<const float4*>(&cpart[0][jj][c4 * 4]);
        const float4 a1 = *reinterpret_cast<const float4*>(&cpart[1][jj][c4 * 4]);
        const float4 a2 = *reinterpret_cast<const float4*>(&cpart[2][jj][c4 * 4]);
        const float4 a3 = *reinterpret_cast<const float4*>(&cpart[3][jj][c4 * 4]);
        float4 a;
        a.x = (a0.x + a1.x) + (a2.x + a3.x);
        a.y = (a0.y + a1.y) + (a2.y + a3.y);
        a.z = (a0.z + a1.z) + (a2.z + a3.z);
        a.w = (a0.w + a1.w) + (a2.w + a3.w);
        size_t co = ((size_t)(j0 + jj) * NST + bi) * PCH;
        *reinterpret_cast<float4*>(cp + co + c4 * 4) = a;
        if (c4 == 0)
            cp[co + 64] = cpart[0][jj][64] + cpart[1][jj][64]
                        + cpart[2][jj][64] + cpart[3][jj][64];
    }
}

// ---------------- K2: fold 48 strip-partials (line-major), /z -> rcfeat -------
__global__ __launch_bounds__(256) void k_combine(const float* __restrict__ rp,
                                                 const float* __restrict__ cp,
                                                 float* __restrict__ rcfeat) {
    int t = threadIdx.x;
    int r = t >> 4, q = t & 15;
    int L = blockIdx.x * 16 + r;
    int side = blockIdx.y;
    const float* base = (side ? cp : rp) + (size_t)L * NST * PCH;

    float4 acc = make_float4(0.f, 0.f, 0.f, 0.f);
    float z = 0.f;
    #pragma unroll 4
    for (int s = 0; s < NST; ++s) {
        const float4 v = *reinterpret_cast<const float4*>(base + s * PCH + q * 4);
        acc.x += v.x; acc.y += v.y; acc.z += v.z; acc.w += v.w;
        z += base[s * PCH + 64];
    }
    float inv = 1.0f / z;
    acc.x *= inv; acc.y *= inv; acc.z *= inv; acc.w *= inv;
    *reinterpret_cast<float4*>(rcfeat + (size_t)side * LL * CT
                               + (size_t)L * CT + q * 4) = acc;
}

// ---------------- K3: diag gather + LN + (x @ W + b) [*sigma] ----------------
__global__ __launch_bounds__(256) void k_final(const float* __restrict__ feat,
                                               const float* __restrict__ rcfeat,
                                               const float* __restrict__ ln_g,
                                               const float* __restrict__ ln_b,
                                               const float* __restrict__ WU,
                                               const float* __restrict__ bU,
                                               const float* __restrict__ WV,
                                               const float* __restrict__ bV,
                                               const float* __restrict__ sigma,
                                               float* __restrict__ out) {
    __shared__ float xbuf[8][KD];
    int t = threadIdx.x;
    int wid = t >> 6, l = t & 63;
    int r0 = blockIdx.x * 8;
    int right = blockIdx.y;
    const float* rfeat = rcfeat;
    const float* cfeat = rcfeat + LL * CT;

    for (int r = wid; r < 8; r += 4) {
        int i = r0 + r;
        float d  = feat[((size_t)i * LL + i) * CT + l];
        float rv = rfeat[(size_t)i * CT + l];
        float cv = cfeat[(size_t)i * CT + l];
        float sum = d + rv + cv;
        #pragma unroll
        for (int o = 32; o; o >>= 1) sum += __shfl_xor(sum, o);
        float mu = sum * (1.0f / 192.0f);
        float d0 = d - mu, d1 = rv - mu, d2 = cv - mu;
        float sq = d0 * d0 + d1 * d1 + d2 * d2;
        #pragma unroll
        for (int o = 32; o; o >>= 1) sq += __shfl_xor(sq, o);
        float rstd = rsqrtf(sq * (1.0f / 192.0f) + 1e-5f);
        float h0 = d0 * rstd, h1 = d1 * rstd, h2 = d2 * rstd;
        float a1 = right ? h2 : h1;
        float a2 = right ? h1 : h2;
        xbuf[r][l]       = h0 * ln_g[l]       + ln_b[l];
        xbuf[r][64 + l]  = a1 * ln_g[64 + l]  + ln_b[64 + l];
        xbuf[r][128 + l] = a2 * ln_g[128 + l] + ln_b[128 + l];
    }
    __syncthreads();

    const float* W    = right ? WV : WU;
    const float* bias = right ? bV : bU;
    int o = blockIdx.z * 512 + t * 2;       // 2 columns per thread
    float2 acc[8];
    #pragma unroll
    for (int r = 0; r < 8; ++r) acc[r] = make_float2(0.f, 0.f);

    for (int k = 0; k < KD; k += 4) {
        float4 xr[8];
        #pragma unroll
        for (int r = 0; r < 8; ++r)
            xr[r] = *reinterpret_cast<const float4*>(&xbuf[r][k]);
        #pragma unroll
        for (int kk = 0; kk < 4; ++kk) {
            const float2 wv = *reinterpret_cast<const float2*>(W + (size_t)(k + kk) * OC + o);
            #pragma unroll
            for (int r = 0; r < 8; ++r) {
                float xv = (&xr[r].x)[kk];
                acc[r].x = fmaf(xv, wv.x, acc[r].x);
                acc[r].y = fmaf(xv, wv.y, acc[r].y);
            }
        }
    }

    const float2 bb = *reinterpret_cast<const float2*>(bias + o);
    float sg = right ? 1.0f : sigma[o >> 7];
    float* obase = out + (right ? (size_t)LL * OC : 0);
    #pragma unroll
    for (int r = 0; r < 8; ++r) {
        float2 v;
        v.x = (acc[r].x + bb.x) * sg;
        v.y = (acc[r].y + bb.y) * sg;
        *reinterpret_cast<float2*>(obase + (size_t)(r0 + r) * OC + o) = v;
    }
}

extern "C" void kernel_launch(void* const* d_in, const int* in_sizes, int n_in,
                              void* d_out, int out_size, void* d_ws, size_t ws_size,
                              hipStream_t stream) {
    const float* feat  = (const float*)d_in[0];
    const float* Wq    = (const float*)d_in[1];
    const float* bq    = (const float*)d_in[2];
    const float* ln_g  = (const float*)d_in[3];
    const float* ln_b  = (const float*)d_in[4];
    const float* WU    = (const float*)d_in[5];
    const float* bU    = (const float*)d_in[6];
    const float* WV    = (const float*)d_in[7];
    const float* bV    = (const float*)d_in[8];
    const float* sigma = (const float*)d_in[9];
    float* out = (float*)d_out;

    float* ws     = (float*)d_ws;
    float* rp     = ws;                                  // LL*NST*PCH
    float* cp     = rp + (size_t)LL * NST * PCH;         // LL*NST*PCH
    float* rcfeat = cp + (size_t)LL * NST * PCH;         // 2*LL*CT

    hipLaunchKernelGGL(k_fused, dim3(NST, NST), dim3(256), 0, stream,
                       feat, Wq, bq, rp, cp);
    hipLaunchKernelGGL(k_combine, dim3(LL / 16, 2), dim3(256), 0, stream,
                       rp, cp, rcfeat);
    hipLaunchKernelGGL(k_final, dim3(LL / 8, 2, 2), dim3(256), 0, stream,
                       feat, rcfeat, ln_g, ln_b, WU, bU, WV, bV, sigma, out);
}